// Round 1
// baseline (272.683 us; speedup 1.0000x reference)
//
#include <hip/hip_runtime.h>

#define H_ 480
#define W_ 640
#define HW 307200
#define NN 128
#define QQ 8192
#define KK 10

// ws layout (bytes)
#define WS_FLAG   0
#define WS_ACC    64        // 128*12 floats = 6144 B
#define WS_ABD    8192      // 128*8 floats  = 4096 B
#define WS_VBITS  16384     // 4800 * 8      = 38400 B
#define WS_PRIO   65536     // 307200*4      = 1228800 B
#define WS_ZERO_BYTES (65536 + HW*4)

// ---- detect how the harness stored the bool masks -------------------------
// int32 storage: every 32-bit word is 0 or 1.
// uint8 storage: random 0/1 bytes -> many words > 1, never 0x3F800000.
// float32 storage: words are 0x00000000 or 0x3F800000.
__global__ void detect_k(const unsigned int* __restrict__ gm, int* __restrict__ flag)
{
    int f = 0;
    for (int i = threadIdx.x; i < 4096; i += 64) {
        unsigned int v = gm[i];
        if (v == 0x3F800000u) f = 2;
        else if (v > 1u && f == 0) f = 1;
    }
    atomicMax(flag, f);
}

// ---- prep: out = d0, pack (gt_depth > MIN_DEPTH) into bit array -----------
__global__ __launch_bounds__(256) void prep_k(const float* __restrict__ d0,
                                              const float* __restrict__ gtd,
                                              float* __restrict__ out,
                                              unsigned long long* __restrict__ vbits)
{
    const int pix = blockIdx.x * 256 + threadIdx.x;
    const float d = d0[pix];
    out[pix] = d;
    const bool v = gtd[pix] > 0.1f;
    const unsigned long long b = __ballot(v);
    if ((threadIdx.x & 63) == 0) vbits[pix >> 6] = b;
}

// ---- main reduction: per (pixel-chunk, n) accumulate M, rhs ---------------
__global__ __launch_bounds__(256) void reduce_k(
    const float* __restrict__ d0,
    const void* __restrict__ gmv,
    const void* __restrict__ rmv,
    const float* __restrict__ km,
    const int* __restrict__ flag,
    const unsigned long long* __restrict__ vbits,
    float* __restrict__ acc)
{
    const int n = blockIdx.y;
    const int base = blockIdx.x * 2048;
    const int fmt = *flag;
    const float fx = km[0], fy = km[4];
    const size_t moff = (size_t)n * HW;

    float s0=0.f,s1=0.f,s2=0.f,s3=0.f,s4=0.f,s5=0.f,s6=0.f,s7=0.f,s8=0.f;

    #pragma unroll
    for (int g = 0; g < 2; ++g) {
        const int p0 = base + g * 1024 + (int)threadIdx.x * 4;
        unsigned gb, rb;
        if (fmt == 0) {
            const int4 a = *reinterpret_cast<const int4*>((const int*)gmv + moff + p0);
            const int4 b = *reinterpret_cast<const int4*>((const int*)rmv + moff + p0);
            gb = (unsigned)(a.x!=0) | ((unsigned)(a.y!=0)<<1) | ((unsigned)(a.z!=0)<<2) | ((unsigned)(a.w!=0)<<3);
            rb = (unsigned)(b.x!=0) | ((unsigned)(b.y!=0)<<1) | ((unsigned)(b.z!=0)<<2) | ((unsigned)(b.w!=0)<<3);
        } else if (fmt == 1) {
            const unsigned a = *reinterpret_cast<const unsigned*>((const unsigned char*)gmv + moff + p0);
            const unsigned b = *reinterpret_cast<const unsigned*>((const unsigned char*)rmv + moff + p0);
            gb = (unsigned)((a&0xFFu)!=0) | ((unsigned)(((a>>8)&0xFFu)!=0)<<1) |
                 ((unsigned)(((a>>16)&0xFFu)!=0)<<2) | ((unsigned)((a>>24)!=0)<<3);
            rb = (unsigned)((b&0xFFu)!=0) | ((unsigned)(((b>>8)&0xFFu)!=0)<<1) |
                 ((unsigned)(((b>>16)&0xFFu)!=0)<<2) | ((unsigned)((b>>24)!=0)<<3);
        } else {
            const float4 a = *reinterpret_cast<const float4*>((const float*)gmv + moff + p0);
            const float4 b = *reinterpret_cast<const float4*>((const float*)rmv + moff + p0);
            gb = (unsigned)(a.x!=0.f) | ((unsigned)(a.y!=0.f)<<1) | ((unsigned)(a.z!=0.f)<<2) | ((unsigned)(a.w!=0.f)<<3);
            rb = (unsigned)(b.x!=0.f) | ((unsigned)(b.y!=0.f)<<1) | ((unsigned)(b.z!=0.f)<<2) | ((unsigned)(b.w!=0.f)<<3);
        }
        const unsigned vb = (unsigned)(vbits[p0 >> 6] >> (p0 & 63)) & 0xFu;
        unsigned bits = gb & rb & vb;
        if (bits) {
            const float4 dv = *reinterpret_cast<const float4*>(d0 + p0);
            while (bits) {
                const int j = __ffs(bits) - 1;
                bits &= bits - 1;
                const int p = p0 + j;
                const int r = p / W_;
                const int c = p - r * W_;
                const float d = (j == 0) ? dv.x : (j == 1) ? dv.y : (j == 2) ? dv.z : dv.w;
                const float ad = fabsf(d);
                const float px = (float)(c - 320) * ad / fx;
                const float py = (float)(r - 240) * ad / fy;
                s0 += px*px; s1 += px*py; s2 += px;
                s3 += py*py; s4 += py;    s5 += 1.0f;
                s6 += px*d;  s7 += py*d;  s8 += d;
            }
        }
    }

    float s[9] = {s0,s1,s2,s3,s4,s5,s6,s7,s8};
    #pragma unroll
    for (int off = 32; off > 0; off >>= 1) {
        #pragma unroll
        for (int i = 0; i < 9; ++i) s[i] += __shfl_down(s[i], off);
    }
    __shared__ float ls[4][9];
    const int wave = threadIdx.x >> 6, lane = threadIdx.x & 63;
    if (lane == 0) {
        #pragma unroll
        for (int i = 0; i < 9; ++i) ls[wave][i] = s[i];
    }
    __syncthreads();
    if (threadIdx.x == 0) {
        #pragma unroll
        for (int i = 0; i < 9; ++i) {
            atomicAdd(&acc[n*12 + i], ls[0][i] + ls[1][i] + ls[2][i] + ls[3][i]);
        }
    }
}

// ---- per-n 3x3 solve (Cramer, double), ok gate, mean(pd/den) --------------
__global__ void solve_k(const float* __restrict__ acc,
                        const float* __restrict__ d0,
                        const float* __restrict__ km,
                        const int* __restrict__ xp,
                        const int* __restrict__ yp,
                        float* __restrict__ abd)
{
    const int n = blockIdx.x * blockDim.x + threadIdx.x;
    if (n >= NN) return;
    const float* s = acc + n * 12;
    const double M00=s[0], M01=s[1], M02=s[2], M11=s[3], M12=s[4], M22=s[5];
    const double r0=s[6], r1=s[7], r2=s[8];
    const double cnt = M22;
    const double c00 = M11*M22 - M12*M12;
    const double c01 = M01*M22 - M12*M02;
    const double c02 = M01*M12 - M11*M02;
    const double det = M00*c00 - M01*c01 + M02*c02;
    const bool ok = (fabs(det) > 1e-8) && (cnt >= 3.0);
    float a = 0.f, b = 0.f, dc = 0.f, scale = 0.f;
    if (ok) {
        const double inv = 1.0 / det;
        const double t1 = r1*M22 - r2*M12;
        const double t2 = M01*r2 - r1*M02;
        const double x0 = (r0*c00 - M01*t1 + M02*(r1*M12 - r2*M11)) * inv;
        const double x1 = (M00*t1 - r0*c01 + M02*t2) * inv;
        const double x2 = (M00*(M11*r2 - r1*M12) - M01*t2 + r0*c02) * inv;
        a = (float)x0; b = (float)x1; dc = (float)x2;
        const float fx = km[0], fy = km[4];
        float sum = 0.0f;
        for (int k = 0; k < KK; ++k) {
            const int xi = xp[n*KK + k], yi = yp[n*KK + k];
            const float dd = d0[xi * W_ + yi];
            const float ad = fabsf(dd);
            const float ppx = (float)(yi - 320) * ad / fx;
            const float ppy = (float)(xi - 240) * ad / fy;
            const float den = a * ppx + b * ppy + dc;
            sum += dd / den;
        }
        scale = sum / (float)KK;
    }
    abd[n*8+0] = a; abd[n*8+1] = b; abd[n*8+2] = dc;
    abd[n*8+3] = scale;
    abd[n*8+4] = ok ? 1.0f : 0.0f;
}

// ---- scatter pass A: priority = max ok n per pixel ------------------------
__global__ __launch_bounds__(256) void prio_k(const int* __restrict__ xq,
                                              const int* __restrict__ yq,
                                              const float* __restrict__ abd,
                                              int* __restrict__ prio)
{
    const int idx = blockIdx.x * 256 + threadIdx.x;
    const int n = idx >> 13;
    if (abd[n*8+4] == 0.0f) return;
    const int pix = xq[idx] * W_ + yq[idx];
    atomicMax(prio + pix, n + 1);
}

// ---- scatter pass B: winner writes its value ------------------------------
__global__ __launch_bounds__(256) void write_k(const int* __restrict__ xq,
                                               const int* __restrict__ yq,
                                               const float* __restrict__ abd,
                                               const int* __restrict__ prio,
                                               const float* __restrict__ d0,
                                               const float* __restrict__ km,
                                               float* __restrict__ out)
{
    const int idx = blockIdx.x * 256 + threadIdx.x;
    const int n = idx >> 13;
    if (abd[n*8+4] == 0.0f) return;
    const int xi = xq[idx], yi = yq[idx];
    const int pix = xi * W_ + yi;
    if (prio[pix] != n + 1) return;
    const float fx = km[0], fy = km[4];
    const float dd = d0[pix];
    const float ad = fabsf(dd);
    const float qx = (float)(yi - 320) * ad / fx;
    const float qy = (float)(xi - 240) * ad / fy;
    const float val = (abd[n*8+0]*qx + abd[n*8+1]*qy + abd[n*8+2]) * abd[n*8+3];
    out[pix] = val;
}

extern "C" void kernel_launch(void* const* d_in, const int* in_sizes, int n_in,
                              void* d_out, int out_size, void* d_ws, size_t ws_size,
                              hipStream_t stream)
{
    const float* d0  = (const float*)d_in[0];
    const void*  gm  = d_in[1];
    const float* gtd = (const float*)d_in[2];
    const float* km  = (const float*)d_in[3];
    const void*  rm  = d_in[4];
    const int*   xq  = (const int*)d_in[5];
    const int*   yq  = (const int*)d_in[6];
    const int*   xp  = (const int*)d_in[7];
    const int*   yp  = (const int*)d_in[8];
    float* out = (float*)d_out;
    char*  ws  = (char*)d_ws;

    int* flag = (int*)(ws + WS_FLAG);
    float* acc = (float*)(ws + WS_ACC);
    float* abd = (float*)(ws + WS_ABD);
    unsigned long long* vbits = (unsigned long long*)(ws + WS_VBITS);
    int* prio = (int*)(ws + WS_PRIO);

    hipMemsetAsync(d_ws, 0, WS_ZERO_BYTES, stream);
    detect_k<<<1, 64, 0, stream>>>((const unsigned int*)gm, flag);
    prep_k<<<HW / 256, 256, 0, stream>>>(d0, gtd, out, vbits);
    reduce_k<<<dim3(150, NN), 256, 0, stream>>>(d0, gm, rm, km, flag, vbits, acc);
    solve_k<<<2, 64, 0, stream>>>(acc, d0, km, xp, yp, abd);
    prio_k<<<(NN * QQ) / 256, 256, 0, stream>>>(xq, yq, abd, prio);
    write_k<<<(NN * QQ) / 256, 256, 0, stream>>>(xq, yq, abd, prio, d0, km, out);
}

// Round 3
// 141.567 us; speedup vs baseline: 1.9262x; 1.9262x over previous
//
#include <hip/hip_runtime.h>

#define H_ 480
#define W_ 640
#define HW 307200
#define NN 128
#define QQ 8192
#define KK 10
#define G_ 6
#define PIXB 6144   // 256 threads * 4 px * G_ iters

// ws layout (bytes)
#define WS_FLAG   0
#define WS_ACC    64        // 128*12 floats = 6144 B
#define WS_ABD    8192      // 128*8 floats  = 4096 B
#define WS_VBITS  16384     // 4800 * 8      = 38400 B
#define WS_PRIO   65536     // 307200*4

// ---- prep: detect mask format (block 0), pack valid bits, zero prio/acc ---
__global__ __launch_bounds__(256) void prep_k(const unsigned int* __restrict__ gm,
                                              const float* __restrict__ gtd,
                                              unsigned long long* __restrict__ vbits,
                                              int* __restrict__ prio,
                                              float* __restrict__ acc,
                                              int* __restrict__ flag)
{
    const int pix = blockIdx.x * 256 + threadIdx.x;
    prio[pix] = 0;
    if (pix < NN * 12) acc[pix] = 0.0f;
    const bool v = gtd[pix] > 0.1f;
    const unsigned long long b = __ballot(v);
    if ((threadIdx.x & 63) == 0) vbits[pix >> 6] = b;

    if (blockIdx.x == 0) {
        // int32 storage: every word 0/1. uint8: words >1 common, never 0x3F800000.
        // float32: words 0x0 or 0x3F800000.
        __shared__ int sf;
        if (threadIdx.x == 0) sf = 0;
        __syncthreads();
        int f = 0;
        for (int i = threadIdx.x; i < 4096; i += 256) {
            const unsigned int w = gm[i];
            if (w == 0x3F800000u) f |= 2;
            else if (w > 1u) f |= 1;
        }
        if (f) atomicOr(&sf, f);
        __syncthreads();
        if (threadIdx.x == 0) *flag = (sf & 2) ? 2 : ((sf & 1) ? 1 : 0);
    }
}

// ---- main reduction: per (pixel-chunk, n) accumulate M, rhs ---------------
__global__ __launch_bounds__(256) void reduce_k(
    const float* __restrict__ d0,
    const void* __restrict__ gmv,
    const void* __restrict__ rmv,
    const float* __restrict__ km,
    const int* __restrict__ flag,
    const unsigned long long* __restrict__ vbits,
    float* __restrict__ acc)
{
    const int n = blockIdx.y;
    const int base = blockIdx.x * PIXB + (int)threadIdx.x * 4;
    const int fmt = *flag;
    const float rfx = 1.0f / km[0], rfy = 1.0f / km[4];
    const size_t moff = (size_t)n * HW;

    unsigned bitsArr[G_];
    if (fmt == 0) {
        int4 ga[G_], ra[G_];
        #pragma unroll
        for (int g = 0; g < G_; ++g) {
            const int p = base + g * 1024;
            ga[g] = *reinterpret_cast<const int4*>((const int*)gmv + moff + p);
            ra[g] = *reinterpret_cast<const int4*>((const int*)rmv + moff + p);
        }
        #pragma unroll
        for (int g = 0; g < G_; ++g) {
            const unsigned gb = (unsigned)(ga[g].x!=0) | ((unsigned)(ga[g].y!=0)<<1)
                              | ((unsigned)(ga[g].z!=0)<<2) | ((unsigned)(ga[g].w!=0)<<3);
            const unsigned rb = (unsigned)(ra[g].x!=0) | ((unsigned)(ra[g].y!=0)<<1)
                              | ((unsigned)(ra[g].z!=0)<<2) | ((unsigned)(ra[g].w!=0)<<3);
            bitsArr[g] = gb & rb;
        }
    } else if (fmt == 1) {
        unsigned ga[G_], ra[G_];
        #pragma unroll
        for (int g = 0; g < G_; ++g) {
            const int p = base + g * 1024;
            ga[g] = *reinterpret_cast<const unsigned*>((const unsigned char*)gmv + moff + p);
            ra[g] = *reinterpret_cast<const unsigned*>((const unsigned char*)rmv + moff + p);
        }
        #pragma unroll
        for (int g = 0; g < G_; ++g) {
            const unsigned a = ga[g], b = ra[g];
            const unsigned gb = (unsigned)((a&0xFFu)!=0) | ((unsigned)(((a>>8)&0xFFu)!=0)<<1)
                              | ((unsigned)(((a>>16)&0xFFu)!=0)<<2) | ((unsigned)((a>>24)!=0)<<3);
            const unsigned rb = (unsigned)((b&0xFFu)!=0) | ((unsigned)(((b>>8)&0xFFu)!=0)<<1)
                              | ((unsigned)(((b>>16)&0xFFu)!=0)<<2) | ((unsigned)((b>>24)!=0)<<3);
            bitsArr[g] = gb & rb;
        }
    } else {
        float4 ga[G_], ra[G_];
        #pragma unroll
        for (int g = 0; g < G_; ++g) {
            const int p = base + g * 1024;
            ga[g] = *reinterpret_cast<const float4*>((const float*)gmv + moff + p);
            ra[g] = *reinterpret_cast<const float4*>((const float*)rmv + moff + p);
        }
        #pragma unroll
        for (int g = 0; g < G_; ++g) {
            const unsigned gb = (unsigned)(ga[g].x!=0.f) | ((unsigned)(ga[g].y!=0.f)<<1)
                              | ((unsigned)(ga[g].z!=0.f)<<2) | ((unsigned)(ga[g].w!=0.f)<<3);
            const unsigned rb = (unsigned)(ra[g].x!=0.f) | ((unsigned)(ra[g].y!=0.f)<<1)
                              | ((unsigned)(ra[g].z!=0.f)<<2) | ((unsigned)(ra[g].w!=0.f)<<3);
            bitsArr[g] = gb & rb;
        }
    }

    float s0=0.f,s1=0.f,s2=0.f,s3=0.f,s4=0.f,s5=0.f,s6=0.f,s7=0.f,s8=0.f;
    #pragma unroll
    for (int g = 0; g < G_; ++g) {
        const int p0 = base + g * 1024;
        unsigned bits = bitsArr[g] & ((unsigned)(vbits[p0 >> 6] >> (p0 & 63)) & 0xFu);
        if (bits) {
            const float4 dv = *reinterpret_cast<const float4*>(d0 + p0);
            const int r = p0 / W_;                 // 640%4==0: group never spans rows
            const int c0 = p0 - r * W_;
            const float pyb = (float)(r - 240) * rfy;
            while (bits) {
                const int j = __ffs(bits) - 1;
                bits &= bits - 1;
                const float d = (j == 0) ? dv.x : (j == 1) ? dv.y : (j == 2) ? dv.z : dv.w;
                const float ad = fabsf(d);
                const float px = (float)(c0 + j - 320) * ad * rfx;
                const float py = pyb * ad;
                s0 += px*px; s1 += px*py; s2 += px;
                s3 += py*py; s4 += py;    s5 += 1.0f;
                s6 += px*d;  s7 += py*d;  s8 += d;
            }
        }
    }

    float s[9] = {s0,s1,s2,s3,s4,s5,s6,s7,s8};
    #pragma unroll
    for (int off = 32; off > 0; off >>= 1) {
        #pragma unroll
        for (int i = 0; i < 9; ++i) s[i] += __shfl_down(s[i], off);
    }
    __shared__ float ls[4][9];
    const int wave = threadIdx.x >> 6, lane = threadIdx.x & 63;
    if (lane == 0) {
        #pragma unroll
        for (int i = 0; i < 9; ++i) ls[wave][i] = s[i];
    }
    __syncthreads();
    if (threadIdx.x == 0) {
        #pragma unroll
        for (int i = 0; i < 9; ++i)
            atomicAdd(&acc[n*12 + i], ls[0][i] + ls[1][i] + ls[2][i] + ls[3][i]);
    }
}

// ---- per-n 3x3 solve (Cramer, double), ok gate, mean(pd/den) --------------
__global__ void solve_k(const float* __restrict__ acc,
                        const float* __restrict__ d0,
                        const float* __restrict__ km,
                        const int* __restrict__ xp,
                        const int* __restrict__ yp,
                        float* __restrict__ abd)
{
    const int n = blockIdx.x * blockDim.x + threadIdx.x;
    if (n >= NN) return;
    const float* s = acc + n * 12;
    const double M00=s[0], M01=s[1], M02=s[2], M11=s[3], M12=s[4], M22=s[5];
    const double r0=s[6], r1=s[7], r2=s[8];
    const double cnt = M22;
    const double c00 = M11*M22 - M12*M12;
    const double c01 = M01*M22 - M12*M02;
    const double c02 = M01*M12 - M11*M02;
    const double det = M00*c00 - M01*c01 + M02*c02;
    const bool ok = (fabs(det) > 1e-8) && (cnt >= 3.0);
    float a = 0.f, b = 0.f, dc = 0.f, scale = 0.f;
    if (ok) {
        const double inv = 1.0 / det;
        const double t1 = r1*M22 - r2*M12;
        const double t2 = M01*r2 - r1*M02;
        const double x0 = (r0*c00 - M01*t1 + M02*(r1*M12 - r2*M11)) * inv;
        const double x1 = (M00*t1 - r0*c01 + M02*t2) * inv;
        const double x2 = (M00*(M11*r2 - r1*M12) - M01*t2 + r0*c02) * inv;
        a = (float)x0; b = (float)x1; dc = (float)x2;
        const float fx = km[0], fy = km[4];
        float sum = 0.0f;
        for (int k = 0; k < KK; ++k) {
            const int xi = xp[n*KK + k], yi = yp[n*KK + k];
            const float dd = d0[xi * W_ + yi];
            const float ad = fabsf(dd);
            const float ppx = (float)(yi - 320) * ad / fx;
            const float ppy = (float)(xi - 240) * ad / fy;
            const float den = a * ppx + b * ppy + dc;
            sum += dd / den;
        }
        scale = sum / (float)KK;
    }
    abd[n*8+0] = a; abd[n*8+1] = b; abd[n*8+2] = dc;
    abd[n*8+3] = scale;
    abd[n*8+4] = ok ? 1.0f : 0.0f;
}

// ---- scatter pass A: priority = max ok n per pixel, 4 queries/thread ------
__global__ __launch_bounds__(256) void prio_k(const int* __restrict__ xq,
                                              const int* __restrict__ yq,
                                              const float* __restrict__ abd,
                                              int* __restrict__ prio)
{
    const int idx = (blockIdx.x * 256 + threadIdx.x) * 4;   // QQ%4==0 -> same n
    const int n = idx >> 13;
    if (abd[n*8+4] == 0.0f) return;
    const int4 xs = *reinterpret_cast<const int4*>(xq + idx);
    const int4 ys = *reinterpret_cast<const int4*>(yq + idx);
    const int np = n + 1;
    atomicMax(prio + xs.x * W_ + ys.x, np);
    atomicMax(prio + xs.y * W_ + ys.y, np);
    atomicMax(prio + xs.z * W_ + ys.z, np);
    atomicMax(prio + xs.w * W_ + ys.w, np);
}

// ---- final: per pixel, winner n (or passthrough d0) -----------------------
__global__ __launch_bounds__(256) void final_k(const int* __restrict__ prio,
                                               const float* __restrict__ abd,
                                               const float* __restrict__ d0,
                                               const float* __restrict__ km,
                                               float* __restrict__ out)
{
    const int p0 = (blockIdx.x * 256 + threadIdx.x) * 4;
    const int4 pr4 = *reinterpret_cast<const int4*>(prio + p0);
    const float4 dv = *reinterpret_cast<const float4*>(d0 + p0);
    const float rfx = 1.0f / km[0], rfy = 1.0f / km[4];
    const int r = p0 / W_;
    const int c0 = p0 - r * W_;
    const float yv = (float)(r - 240) * rfy;
    const int pr[4] = {pr4.x, pr4.y, pr4.z, pr4.w};
    const float dd[4] = {dv.x, dv.y, dv.z, dv.w};
    float o[4];
    #pragma unroll
    for (int j = 0; j < 4; ++j) {
        float v = dd[j];
        if (pr[j] > 0) {
            const int n = pr[j] - 1;
            const float ad = fabsf(dd[j]);
            const float qx = (float)(c0 + j - 320) * ad * rfx;
            const float qy = yv * ad;
            v = (abd[n*8+0]*qx + abd[n*8+1]*qy + abd[n*8+2]) * abd[n*8+3];
        }
        o[j] = v;
    }
    *reinterpret_cast<float4*>(out + p0) = make_float4(o[0], o[1], o[2], o[3]);
}

extern "C" void kernel_launch(void* const* d_in, const int* in_sizes, int n_in,
                              void* d_out, int out_size, void* d_ws, size_t ws_size,
                              hipStream_t stream)
{
    const float* d0  = (const float*)d_in[0];
    const void*  gm  = d_in[1];
    const float* gtd = (const float*)d_in[2];
    const float* km  = (const float*)d_in[3];
    const void*  rm  = d_in[4];
    const int*   xq  = (const int*)d_in[5];
    const int*   yq  = (const int*)d_in[6];
    const int*   xp  = (const int*)d_in[7];
    const int*   yp  = (const int*)d_in[8];
    float* out = (float*)d_out;
    char*  ws  = (char*)d_ws;

    int* flag = (int*)(ws + WS_FLAG);
    float* acc = (float*)(ws + WS_ACC);
    float* abd = (float*)(ws + WS_ABD);
    unsigned long long* vbits = (unsigned long long*)(ws + WS_VBITS);
    int* prio = (int*)(ws + WS_PRIO);

    prep_k<<<HW / 256, 256, 0, stream>>>((const unsigned int*)gm, gtd, vbits, prio, acc, flag);
    reduce_k<<<dim3(HW / PIXB, NN), 256, 0, stream>>>(d0, gm, rm, km, flag, vbits, acc);
    solve_k<<<2, 64, 0, stream>>>(acc, d0, km, xp, yp, abd);
    prio_k<<<(NN * QQ / 4) / 256, 256, 0, stream>>>(xq, yq, abd, prio);
    final_k<<<(HW / 4) / 256, 256, 0, stream>>>(prio, abd, d0, km, out);
}

// Round 4
// 126.549 us; speedup vs baseline: 2.1548x; 1.1187x over previous
//
#include <hip/hip_runtime.h>

#define H_ 480
#define W_ 640
#define HW 307200
#define NN 128
#define QQ 8192
#define KK 10
#define G_ 6
#define PIXB 6144   // legacy path: 256 threads * 4 px * G_ iters

// ws layout (bytes)
#define WS_FLAG   0
#define WS_ACC    64            // 128*12 floats = 6144 B
#define WS_ABD    8192          // 128*8 floats  = 4096 B
#define WS_VBITS  16384         // 4800 * 8      = 38400 B
#define WS_PRIO   65536         // 307200*4 = 1228800 B
#define WS_PACK   1294336       // 128*4800*8 = 4915200 B
#define WS_NEED   (WS_PACK + (size_t)NN * 4800 * 8)

// ---- prep: detect mask format (block 0), pack valid bits, zero prio/acc ---
__global__ __launch_bounds__(256) void prep_k(const unsigned int* __restrict__ gm,
                                              const float* __restrict__ gtd,
                                              unsigned long long* __restrict__ vbits,
                                              int* __restrict__ prio,
                                              float* __restrict__ acc,
                                              int* __restrict__ flag)
{
    const int pix = blockIdx.x * 256 + threadIdx.x;
    prio[pix] = 0;
    if (pix < NN * 12) acc[pix] = 0.0f;
    const bool v = gtd[pix] > 0.1f;
    const unsigned long long b = __ballot(v);
    if ((threadIdx.x & 63) == 0) vbits[pix >> 6] = b;

    if (blockIdx.x == 0) {
        // int32: every word 0/1. uint8: words >1 common, never 0x3F800000.
        // float32: words 0x0 or 0x3F800000.
        __shared__ int sf;
        if (threadIdx.x == 0) sf = 0;
        __syncthreads();
        int f = 0;
        for (int i = threadIdx.x; i < 4096; i += 256) {
            const unsigned int w = gm[i];
            if (w == 0x3F800000u) f |= 2;
            else if (w > 1u) f |= 1;
        }
        if (f) atomicOr(&sf, f);
        __syncthreads();
        if (threadIdx.x == 0) *flag = (sf & 2) ? 2 : ((sf & 1) ? 1 : 0);
    }
}

// ---- pass 1: pure stream — compress masks to 1 bit/px (8 px per byte) -----
// grid (10, NN), 256 threads; thread handles 15 groups of 8 px.
__global__ __launch_bounds__(256) void compress_k(
    const void* __restrict__ gmv,
    const void* __restrict__ rmv,
    const int* __restrict__ flag,
    const unsigned long long* __restrict__ vbits,
    unsigned char* __restrict__ packed)
{
    const int n = blockIdx.y;
    const int fmt = *flag;
    const unsigned char* __restrict__ vb8 = (const unsigned char*)vbits;
    unsigned char* __restrict__ outp = packed + (size_t)n * 38400;

    if (fmt == 0) {
        const int* gp = (const int*)gmv + (size_t)n * HW;
        const int* rp = (const int*)rmv + (size_t)n * HW;
        #pragma unroll
        for (int k = 0; k < 15; ++k) {
            const int grp = blockIdx.x * 3840 + k * 256 + (int)threadIdx.x;
            const int px = grp * 8;
            const int4 a0 = *reinterpret_cast<const int4*>(gp + px);
            const int4 a1 = *reinterpret_cast<const int4*>(gp + px + 4);
            const int4 b0 = *reinterpret_cast<const int4*>(rp + px);
            const int4 b1 = *reinterpret_cast<const int4*>(rp + px + 4);
            unsigned g8 = (unsigned)(a0.x!=0) | ((unsigned)(a0.y!=0)<<1) | ((unsigned)(a0.z!=0)<<2) | ((unsigned)(a0.w!=0)<<3)
                        | ((unsigned)(a1.x!=0)<<4) | ((unsigned)(a1.y!=0)<<5) | ((unsigned)(a1.z!=0)<<6) | ((unsigned)(a1.w!=0)<<7);
            unsigned r8 = (unsigned)(b0.x!=0) | ((unsigned)(b0.y!=0)<<1) | ((unsigned)(b0.z!=0)<<2) | ((unsigned)(b0.w!=0)<<3)
                        | ((unsigned)(b1.x!=0)<<4) | ((unsigned)(b1.y!=0)<<5) | ((unsigned)(b1.z!=0)<<6) | ((unsigned)(b1.w!=0)<<7);
            outp[grp] = (unsigned char)(g8 & r8 & vb8[grp]);
        }
    } else if (fmt == 1) {
        const unsigned char* gp = (const unsigned char*)gmv + (size_t)n * HW;
        const unsigned char* rp = (const unsigned char*)rmv + (size_t)n * HW;
        #pragma unroll
        for (int k = 0; k < 15; ++k) {
            const int grp = blockIdx.x * 3840 + k * 256 + (int)threadIdx.x;
            const int px = grp * 8;
            const unsigned long long a = *reinterpret_cast<const unsigned long long*>(gp + px);
            const unsigned long long b = *reinterpret_cast<const unsigned long long*>(rp + px);
            unsigned g8 = 0, r8 = 0;
            #pragma unroll
            for (int j = 0; j < 8; ++j) {
                g8 |= (unsigned)(((a >> (8*j)) & 0xFFull) != 0) << j;
                r8 |= (unsigned)(((b >> (8*j)) & 0xFFull) != 0) << j;
            }
            outp[grp] = (unsigned char)(g8 & r8 & vb8[grp]);
        }
    } else {
        const float* gp = (const float*)gmv + (size_t)n * HW;
        const float* rp = (const float*)rmv + (size_t)n * HW;
        #pragma unroll
        for (int k = 0; k < 15; ++k) {
            const int grp = blockIdx.x * 3840 + k * 256 + (int)threadIdx.x;
            const int px = grp * 8;
            const float4 a0 = *reinterpret_cast<const float4*>(gp + px);
            const float4 a1 = *reinterpret_cast<const float4*>(gp + px + 4);
            const float4 b0 = *reinterpret_cast<const float4*>(rp + px);
            const float4 b1 = *reinterpret_cast<const float4*>(rp + px + 4);
            unsigned g8 = (unsigned)(a0.x!=0.f) | ((unsigned)(a0.y!=0.f)<<1) | ((unsigned)(a0.z!=0.f)<<2) | ((unsigned)(a0.w!=0.f)<<3)
                        | ((unsigned)(a1.x!=0.f)<<4) | ((unsigned)(a1.y!=0.f)<<5) | ((unsigned)(a1.z!=0.f)<<6) | ((unsigned)(a1.w!=0.f)<<7);
            unsigned r8 = (unsigned)(b0.x!=0.f) | ((unsigned)(b0.y!=0.f)<<1) | ((unsigned)(b0.z!=0.f)<<2) | ((unsigned)(b0.w!=0.f)<<3)
                        | ((unsigned)(b1.x!=0.f)<<4) | ((unsigned)(b1.y!=0.f)<<5) | ((unsigned)(b1.z!=0.f)<<6) | ((unsigned)(b1.w!=0.f)<<7);
            outp[grp] = (unsigned char)(g8 & r8 & vb8[grp]);
        }
    }
}

// ---- pass 2: per (word-chunk, n) accumulate M, rhs from packed bits -------
// grid (25, NN), 192 threads; one u64 word (64 px) per thread. 25*192=4800.
__global__ __launch_bounds__(192) void reduce2_k(
    const float* __restrict__ d0,
    const unsigned long long* __restrict__ packed,
    const float* __restrict__ km,
    float* __restrict__ acc)
{
    const int n = blockIdx.y;
    const int w = blockIdx.x * 192 + (int)threadIdx.x;   // word index, 0..4799
    unsigned long long bits = packed[(size_t)n * 4800 + w];
    const float rfx = 1.0f / km[0], rfy = 1.0f / km[4];

    float s0=0.f,s1=0.f,s2=0.f,s3=0.f,s4=0.f,s5=0.f,s6=0.f,s7=0.f,s8=0.f;
    if (bits) {
        const int r = w / 10;                  // 10 words per row (640/64)
        const int c0 = (w - r * 10) * 64;
        const float pyb = (float)(r - 240) * rfy;
        const float* drow = d0 + r * W_ + c0;
        while (bits) {
            const int j = __ffsll((unsigned long long)bits) - 1;
            bits &= bits - 1;
            const float d = drow[j];
            const float ad = fabsf(d);
            const float px = (float)(c0 + j - 320) * ad * rfx;
            const float py = pyb * ad;
            s0 += px*px; s1 += px*py; s2 += px;
            s3 += py*py; s4 += py;    s5 += 1.0f;
            s6 += px*d;  s7 += py*d;  s8 += d;
        }
    }

    float s[9] = {s0,s1,s2,s3,s4,s5,s6,s7,s8};
    #pragma unroll
    for (int off = 32; off > 0; off >>= 1) {
        #pragma unroll
        for (int i = 0; i < 9; ++i) s[i] += __shfl_down(s[i], off);
    }
    __shared__ float ls[3][9];
    const int wave = threadIdx.x >> 6, lane = threadIdx.x & 63;
    if (lane == 0) {
        #pragma unroll
        for (int i = 0; i < 9; ++i) ls[wave][i] = s[i];
    }
    __syncthreads();
    if (threadIdx.x < 9) {
        const int i = threadIdx.x;
        atomicAdd(&acc[n*12 + i], ls[0][i] + ls[1][i] + ls[2][i]);
    }
}

// ---- legacy fused reduction (fallback if ws too small) --------------------
__global__ __launch_bounds__(256) void reduce_k(
    const float* __restrict__ d0,
    const void* __restrict__ gmv,
    const void* __restrict__ rmv,
    const float* __restrict__ km,
    const int* __restrict__ flag,
    const unsigned long long* __restrict__ vbits,
    float* __restrict__ acc)
{
    const int n = blockIdx.y;
    const int base = blockIdx.x * PIXB + (int)threadIdx.x * 4;
    const int fmt = *flag;
    const float rfx = 1.0f / km[0], rfy = 1.0f / km[4];
    const size_t moff = (size_t)n * HW;

    unsigned bitsArr[G_];
    if (fmt == 0) {
        int4 ga[G_], ra[G_];
        #pragma unroll
        for (int g = 0; g < G_; ++g) {
            const int p = base + g * 1024;
            ga[g] = *reinterpret_cast<const int4*>((const int*)gmv + moff + p);
            ra[g] = *reinterpret_cast<const int4*>((const int*)rmv + moff + p);
        }
        #pragma unroll
        for (int g = 0; g < G_; ++g) {
            const unsigned gb = (unsigned)(ga[g].x!=0) | ((unsigned)(ga[g].y!=0)<<1)
                              | ((unsigned)(ga[g].z!=0)<<2) | ((unsigned)(ga[g].w!=0)<<3);
            const unsigned rb = (unsigned)(ra[g].x!=0) | ((unsigned)(ra[g].y!=0)<<1)
                              | ((unsigned)(ra[g].z!=0)<<2) | ((unsigned)(ra[g].w!=0)<<3);
            bitsArr[g] = gb & rb;
        }
    } else if (fmt == 1) {
        unsigned ga[G_], ra[G_];
        #pragma unroll
        for (int g = 0; g < G_; ++g) {
            const int p = base + g * 1024;
            ga[g] = *reinterpret_cast<const unsigned*>((const unsigned char*)gmv + moff + p);
            ra[g] = *reinterpret_cast<const unsigned*>((const unsigned char*)rmv + moff + p);
        }
        #pragma unroll
        for (int g = 0; g < G_; ++g) {
            const unsigned a = ga[g], b = ra[g];
            const unsigned gb = (unsigned)((a&0xFFu)!=0) | ((unsigned)(((a>>8)&0xFFu)!=0)<<1)
                              | ((unsigned)(((a>>16)&0xFFu)!=0)<<2) | ((unsigned)((a>>24)!=0)<<3);
            const unsigned rb = (unsigned)((b&0xFFu)!=0) | ((unsigned)(((b>>8)&0xFFu)!=0)<<1)
                              | ((unsigned)(((b>>16)&0xFFu)!=0)<<2) | ((unsigned)((b>>24)!=0)<<3);
            bitsArr[g] = gb & rb;
        }
    } else {
        float4 ga[G_], ra[G_];
        #pragma unroll
        for (int g = 0; g < G_; ++g) {
            const int p = base + g * 1024;
            ga[g] = *reinterpret_cast<const float4*>((const float*)gmv + moff + p);
            ra[g] = *reinterpret_cast<const float4*>((const float*)rmv + moff + p);
        }
        #pragma unroll
        for (int g = 0; g < G_; ++g) {
            const unsigned gb = (unsigned)(ga[g].x!=0.f) | ((unsigned)(ga[g].y!=0.f)<<1)
                              | ((unsigned)(ga[g].z!=0.f)<<2) | ((unsigned)(ga[g].w!=0.f)<<3);
            const unsigned rb = (unsigned)(ra[g].x!=0.f) | ((unsigned)(ra[g].y!=0.f)<<1)
                              | ((unsigned)(ra[g].z!=0.f)<<2) | ((unsigned)(ra[g].w!=0.f)<<3);
            bitsArr[g] = gb & rb;
        }
    }

    float s0=0.f,s1=0.f,s2=0.f,s3=0.f,s4=0.f,s5=0.f,s6=0.f,s7=0.f,s8=0.f;
    #pragma unroll
    for (int g = 0; g < G_; ++g) {
        const int p0 = base + g * 1024;
        unsigned bits = bitsArr[g] & ((unsigned)(vbits[p0 >> 6] >> (p0 & 63)) & 0xFu);
        if (bits) {
            const float4 dv = *reinterpret_cast<const float4*>(d0 + p0);
            const int r = p0 / W_;
            const int c0 = p0 - r * W_;
            const float pyb = (float)(r - 240) * rfy;
            while (bits) {
                const int j = __ffs(bits) - 1;
                bits &= bits - 1;
                const float d = (j == 0) ? dv.x : (j == 1) ? dv.y : (j == 2) ? dv.z : dv.w;
                const float ad = fabsf(d);
                const float px = (float)(c0 + j - 320) * ad * rfx;
                const float py = pyb * ad;
                s0 += px*px; s1 += px*py; s2 += px;
                s3 += py*py; s4 += py;    s5 += 1.0f;
                s6 += px*d;  s7 += py*d;  s8 += d;
            }
        }
    }

    float s[9] = {s0,s1,s2,s3,s4,s5,s6,s7,s8};
    #pragma unroll
    for (int off = 32; off > 0; off >>= 1) {
        #pragma unroll
        for (int i = 0; i < 9; ++i) s[i] += __shfl_down(s[i], off);
    }
    __shared__ float ls[4][9];
    const int wave = threadIdx.x >> 6, lane = threadIdx.x & 63;
    if (lane == 0) {
        #pragma unroll
        for (int i = 0; i < 9; ++i) ls[wave][i] = s[i];
    }
    __syncthreads();
    if (threadIdx.x == 0) {
        #pragma unroll
        for (int i = 0; i < 9; ++i)
            atomicAdd(&acc[n*12 + i], ls[0][i] + ls[1][i] + ls[2][i] + ls[3][i]);
    }
}

// ---- per-n 3x3 solve (Cramer, double), ok gate, mean(pd/den) --------------
__global__ void solve_k(const float* __restrict__ acc,
                        const float* __restrict__ d0,
                        const float* __restrict__ km,
                        const int* __restrict__ xp,
                        const int* __restrict__ yp,
                        float* __restrict__ abd)
{
    const int n = blockIdx.x * blockDim.x + threadIdx.x;
    if (n >= NN) return;
    const float* s = acc + n * 12;
    const double M00=s[0], M01=s[1], M02=s[2], M11=s[3], M12=s[4], M22=s[5];
    const double r0=s[6], r1=s[7], r2=s[8];
    const double cnt = M22;
    const double c00 = M11*M22 - M12*M12;
    const double c01 = M01*M22 - M12*M02;
    const double c02 = M01*M12 - M11*M02;
    const double det = M00*c00 - M01*c01 + M02*c02;
    const bool ok = (fabs(det) > 1e-8) && (cnt >= 3.0);
    float a = 0.f, b = 0.f, dc = 0.f, scale = 0.f;
    if (ok) {
        const double inv = 1.0 / det;
        const double t1 = r1*M22 - r2*M12;
        const double t2 = M01*r2 - r1*M02;
        const double x0 = (r0*c00 - M01*t1 + M02*(r1*M12 - r2*M11)) * inv;
        const double x1 = (M00*t1 - r0*c01 + M02*t2) * inv;
        const double x2 = (M00*(M11*r2 - r1*M12) - M01*t2 + r0*c02) * inv;
        a = (float)x0; b = (float)x1; dc = (float)x2;
        const float fx = km[0], fy = km[4];
        float sum = 0.0f;
        for (int k = 0; k < KK; ++k) {
            const int xi = xp[n*KK + k], yi = yp[n*KK + k];
            const float dd = d0[xi * W_ + yi];
            const float ad = fabsf(dd);
            const float ppx = (float)(yi - 320) * ad / fx;
            const float ppy = (float)(xi - 240) * ad / fy;
            const float den = a * ppx + b * ppy + dc;
            sum += dd / den;
        }
        scale = sum / (float)KK;
    }
    abd[n*8+0] = a; abd[n*8+1] = b; abd[n*8+2] = dc;
    abd[n*8+3] = scale;
    abd[n*8+4] = ok ? 1.0f : 0.0f;
}

// ---- scatter pass A: priority = max ok n per pixel, 4 queries/thread ------
__global__ __launch_bounds__(256) void prio_k(const int* __restrict__ xq,
                                              const int* __restrict__ yq,
                                              const float* __restrict__ abd,
                                              int* __restrict__ prio)
{
    const int idx = (blockIdx.x * 256 + threadIdx.x) * 4;   // QQ%4==0 -> same n
    const int n = idx >> 13;
    if (abd[n*8+4] == 0.0f) return;
    const int4 xs = *reinterpret_cast<const int4*>(xq + idx);
    const int4 ys = *reinterpret_cast<const int4*>(yq + idx);
    const int np = n + 1;
    atomicMax(prio + xs.x * W_ + ys.x, np);
    atomicMax(prio + xs.y * W_ + ys.y, np);
    atomicMax(prio + xs.z * W_ + ys.z, np);
    atomicMax(prio + xs.w * W_ + ys.w, np);
}

// ---- final: per pixel, winner n (or passthrough d0) -----------------------
__global__ __launch_bounds__(256) void final_k(const int* __restrict__ prio,
                                               const float* __restrict__ abd,
                                               const float* __restrict__ d0,
                                               const float* __restrict__ km,
                                               float* __restrict__ out)
{
    const int p0 = (blockIdx.x * 256 + threadIdx.x) * 4;
    const int4 pr4 = *reinterpret_cast<const int4*>(prio + p0);
    const float4 dv = *reinterpret_cast<const float4*>(d0 + p0);
    const float rfx = 1.0f / km[0], rfy = 1.0f / km[4];
    const int r = p0 / W_;
    const int c0 = p0 - r * W_;
    const float yv = (float)(r - 240) * rfy;
    const int pr[4] = {pr4.x, pr4.y, pr4.z, pr4.w};
    const float dd[4] = {dv.x, dv.y, dv.z, dv.w};
    float o[4];
    #pragma unroll
    for (int j = 0; j < 4; ++j) {
        float v = dd[j];
        if (pr[j] > 0) {
            const int n = pr[j] - 1;
            const float ad = fabsf(dd[j]);
            const float qx = (float)(c0 + j - 320) * ad * rfx;
            const float qy = yv * ad;
            v = (abd[n*8+0]*qx + abd[n*8+1]*qy + abd[n*8+2]) * abd[n*8+3];
        }
        o[j] = v;
    }
    *reinterpret_cast<float4*>(out + p0) = make_float4(o[0], o[1], o[2], o[3]);
}

extern "C" void kernel_launch(void* const* d_in, const int* in_sizes, int n_in,
                              void* d_out, int out_size, void* d_ws, size_t ws_size,
                              hipStream_t stream)
{
    const float* d0  = (const float*)d_in[0];
    const void*  gm  = d_in[1];
    const float* gtd = (const float*)d_in[2];
    const float* km  = (const float*)d_in[3];
    const void*  rm  = d_in[4];
    const int*   xq  = (const int*)d_in[5];
    const int*   yq  = (const int*)d_in[6];
    const int*   xp  = (const int*)d_in[7];
    const int*   yp  = (const int*)d_in[8];
    float* out = (float*)d_out;
    char*  ws  = (char*)d_ws;

    int* flag = (int*)(ws + WS_FLAG);
    float* acc = (float*)(ws + WS_ACC);
    float* abd = (float*)(ws + WS_ABD);
    unsigned long long* vbits = (unsigned long long*)(ws + WS_VBITS);
    int* prio = (int*)(ws + WS_PRIO);
    unsigned char* packed = (unsigned char*)(ws + WS_PACK);

    prep_k<<<HW / 256, 256, 0, stream>>>((const unsigned int*)gm, gtd, vbits, prio, acc, flag);
    if (ws_size >= WS_NEED) {
        compress_k<<<dim3(10, NN), 256, 0, stream>>>(gm, rm, flag, vbits, packed);
        reduce2_k<<<dim3(25, NN), 192, 0, stream>>>(d0, (const unsigned long long*)packed, km, acc);
    } else {
        reduce_k<<<dim3(HW / PIXB, NN), 256, 0, stream>>>(d0, gm, rm, km, flag, vbits, acc);
    }
    solve_k<<<2, 64, 0, stream>>>(acc, d0, km, xp, yp, abd);
    prio_k<<<(NN * QQ / 4) / 256, 256, 0, stream>>>(xq, yq, abd, prio);
    final_k<<<(HW / 4) / 256, 256, 0, stream>>>(prio, abd, d0, km, out);
}

// Round 6
// 124.515 us; speedup vs baseline: 2.1900x; 1.0163x over previous
//
#include <hip/hip_runtime.h>

#define H_ 480
#define W_ 640
#define HW 307200
#define NN 128
#define QQ 8192
#define KK 10
#define G_ 6
#define PIXB 6144   // legacy path: 256 threads * 4 px * G_ iters

// ws layout (bytes)
#define WS_FLAG   0
#define WS_ACC    64            // 128*12 floats = 6144 B
#define WS_ABD    8192          // 128*8 floats  = 4096 B
#define WS_VBITS  16384         // 4800 * 8      = 38400 B
#define WS_PRIO   65536         // 307200*4 = 1228800 B
#define WS_PACK   1294336       // 128*4800*8 = 4915200 B
#define WS_NEED   (WS_PACK + (size_t)NN * 4800 * 8)

// ---- prep: detect mask format (block 0), pack valid bits, zero prio/acc ---
__global__ __launch_bounds__(256) void prep_k(const unsigned int* __restrict__ gm,
                                              const float* __restrict__ gtd,
                                              unsigned long long* __restrict__ vbits,
                                              int* __restrict__ prio,
                                              float* __restrict__ acc,
                                              int* __restrict__ flag)
{
    const int pix = blockIdx.x * 256 + threadIdx.x;
    prio[pix] = 0;
    if (pix < NN * 12) acc[pix] = 0.0f;
    const bool v = gtd[pix] > 0.1f;
    const unsigned long long b = __ballot(v);
    if ((threadIdx.x & 63) == 0) vbits[pix >> 6] = b;

    if (blockIdx.x == 0) {
        // int32: every word 0/1. uint8: words >1 (but < 0x3F800000) common.
        // float32: words 0x0 or 0x3F800000.
        __shared__ int sf;
        if (threadIdx.x == 0) sf = 0;
        __syncthreads();
        int f = 0;
        for (int i = threadIdx.x; i < 4096; i += 256) {
            const unsigned int w = gm[i];
            if (w == 0x3F800000u) f |= 2;
            else if (w > 1u) f |= 1;
        }
        if (f) atomicOr(&sf, f);
        __syncthreads();
        if (threadIdx.x == 0) *flag = (sf & 2) ? 2 : ((sf & 1) ? 1 : 0);
    }
}

// ---- pass 1: pure stream — compress masks to 1 bit/px (8 px per byte) -----
// grid (50, NN), 256 threads; thread handles 3 groups of 8 px.
// All loads issued before any consumption (sched_barrier pins the order);
// __launch_bounds__(256,4) lifts the VGPR cap to 128 so they stay in flight.
__global__ __launch_bounds__(256, 4) void compress_k(
    const void* __restrict__ gmv,
    const void* __restrict__ rmv,
    const int* __restrict__ flag,
    const unsigned long long* __restrict__ vbits,
    unsigned char* __restrict__ packed)
{
    const int n = blockIdx.y;
    const int fmt = *flag;
    const unsigned char* __restrict__ vb8 = (const unsigned char*)vbits;
    unsigned char* __restrict__ outp = packed + (size_t)n * 38400;
    const int g0 = blockIdx.x * 768 + (int)threadIdx.x;   // groups g0, g0+256, g0+512

    if (fmt != 1) {
        // 4-byte elements (int32 0/1 or float32 0.0/1.0): (a&b)!=0 == both-true
        const unsigned* gp = (const unsigned*)gmv + (size_t)n * HW;
        const unsigned* rp = (const unsigned*)rmv + (size_t)n * HW;
        uint4 ga0[3], ga1[3], ra0[3], ra1[3];
        unsigned char vbb[3];
        #pragma unroll
        for (int k = 0; k < 3; ++k) {
            const int px = (g0 + k * 256) * 8;
            ga0[k] = *reinterpret_cast<const uint4*>(gp + px);
            ga1[k] = *reinterpret_cast<const uint4*>(gp + px + 4);
            ra0[k] = *reinterpret_cast<const uint4*>(rp + px);
            ra1[k] = *reinterpret_cast<const uint4*>(rp + px + 4);
        }
        #pragma unroll
        for (int k = 0; k < 3; ++k) vbb[k] = vb8[g0 + k * 256];
        __builtin_amdgcn_sched_barrier(0);
        #pragma unroll
        for (int k = 0; k < 3; ++k) {
            const unsigned m =
                  ((ga0[k].x & ra0[k].x) != 0u ? 0x01u : 0u)
                | ((ga0[k].y & ra0[k].y) != 0u ? 0x02u : 0u)
                | ((ga0[k].z & ra0[k].z) != 0u ? 0x04u : 0u)
                | ((ga0[k].w & ra0[k].w) != 0u ? 0x08u : 0u)
                | ((ga1[k].x & ra1[k].x) != 0u ? 0x10u : 0u)
                | ((ga1[k].y & ra1[k].y) != 0u ? 0x20u : 0u)
                | ((ga1[k].z & ra1[k].z) != 0u ? 0x40u : 0u)
                | ((ga1[k].w & ra1[k].w) != 0u ? 0x80u : 0u);
            outp[g0 + k * 256] = (unsigned char)(m & vbb[k]);
        }
    } else {
        // 1-byte elements
        const unsigned char* gp = (const unsigned char*)gmv + (size_t)n * HW;
        const unsigned char* rp = (const unsigned char*)rmv + (size_t)n * HW;
        unsigned long long ga[3], ra[3];
        unsigned char vbb[3];
        #pragma unroll
        for (int k = 0; k < 3; ++k) {
            const int px = (g0 + k * 256) * 8;
            ga[k] = *reinterpret_cast<const unsigned long long*>(gp + px);
            ra[k] = *reinterpret_cast<const unsigned long long*>(rp + px);
        }
        #pragma unroll
        for (int k = 0; k < 3; ++k) vbb[k] = vb8[g0 + k * 256];
        __builtin_amdgcn_sched_barrier(0);
        #pragma unroll
        for (int k = 0; k < 3; ++k) {
            const unsigned long long ab = ga[k] & ra[k];   // bytes are 0/1
            unsigned m = 0;
            #pragma unroll
            for (int j = 0; j < 8; ++j)
                m |= (unsigned)(((ab >> (8*j)) & 0xFFull) != 0) << j;
            outp[g0 + k * 256] = (unsigned char)(m & vbb[k]);
        }
    }
}

// ---- pass 2: per (word-chunk, n) accumulate M, rhs from packed bits -------
// grid (25, NN), 192 threads; one u64 word (64 px) per thread. 25*192=4800.
__global__ __launch_bounds__(192) void reduce2_k(
    const float* __restrict__ d0,
    const unsigned long long* __restrict__ packed,
    const float* __restrict__ km,
    float* __restrict__ acc)
{
    const int n = blockIdx.y;
    const int w = blockIdx.x * 192 + (int)threadIdx.x;   // word index, 0..4799
    unsigned long long bits = packed[(size_t)n * 4800 + w];
    const float rfx = 1.0f / km[0], rfy = 1.0f / km[4];

    float s0=0.f,s1=0.f,s2=0.f,s3=0.f,s4=0.f,s5=0.f,s6=0.f,s7=0.f,s8=0.f;
    if (bits) {
        const int r = w / 10;                  // 10 words per row (640/64)
        const int c0 = (w - r * 10) * 64;
        const float pyb = (float)(r - 240) * rfy;
        const float* drow = d0 + r * W_ + c0;
        while (bits) {
            const int j = __ffsll((unsigned long long)bits) - 1;
            bits &= bits - 1;
            const float d = drow[j];
            const float ad = fabsf(d);
            const float px = (float)(c0 + j - 320) * ad * rfx;
            const float py = pyb * ad;
            s0 += px*px; s1 += px*py; s2 += px;
            s3 += py*py; s4 += py;    s5 += 1.0f;
            s6 += px*d;  s7 += py*d;  s8 += d;
        }
    }

    float s[9] = {s0,s1,s2,s3,s4,s5,s6,s7,s8};
    #pragma unroll
    for (int off = 32; off > 0; off >>= 1) {
        #pragma unroll
        for (int i = 0; i < 9; ++i) s[i] += __shfl_down(s[i], off);
    }
    __shared__ float ls[3][9];
    const int wave = threadIdx.x >> 6, lane = threadIdx.x & 63;
    if (lane == 0) {
        #pragma unroll
        for (int i = 0; i < 9; ++i) ls[wave][i] = s[i];
    }
    __syncthreads();
    if (threadIdx.x < 9) {
        const int i = threadIdx.x;
        atomicAdd(&acc[n*12 + i], ls[0][i] + ls[1][i] + ls[2][i]);
    }
}

// ---- legacy fused reduction (fallback if ws too small) --------------------
__global__ __launch_bounds__(256) void reduce_k(
    const float* __restrict__ d0,
    const void* __restrict__ gmv,
    const void* __restrict__ rmv,
    const float* __restrict__ km,
    const int* __restrict__ flag,
    const unsigned long long* __restrict__ vbits,
    float* __restrict__ acc)
{
    const int n = blockIdx.y;
    const int base = blockIdx.x * PIXB + (int)threadIdx.x * 4;
    const int fmt = *flag;
    const float rfx = 1.0f / km[0], rfy = 1.0f / km[4];
    const size_t moff = (size_t)n * HW;

    unsigned bitsArr[G_];
    if (fmt != 1) {
        uint4 ga[G_], ra[G_];
        #pragma unroll
        for (int g = 0; g < G_; ++g) {
            const int p = base + g * 1024;
            ga[g] = *reinterpret_cast<const uint4*>((const unsigned*)gmv + moff + p);
            ra[g] = *reinterpret_cast<const uint4*>((const unsigned*)rmv + moff + p);
        }
        #pragma unroll
        for (int g = 0; g < G_; ++g) {
            bitsArr[g] = ((ga[g].x & ra[g].x) != 0u ? 1u : 0u)
                       | ((ga[g].y & ra[g].y) != 0u ? 2u : 0u)
                       | ((ga[g].z & ra[g].z) != 0u ? 4u : 0u)
                       | ((ga[g].w & ra[g].w) != 0u ? 8u : 0u);
        }
    } else {
        unsigned ga[G_], ra[G_];
        #pragma unroll
        for (int g = 0; g < G_; ++g) {
            const int p = base + g * 1024;
            ga[g] = *reinterpret_cast<const unsigned*>((const unsigned char*)gmv + moff + p);
            ra[g] = *reinterpret_cast<const unsigned*>((const unsigned char*)rmv + moff + p);
        }
        #pragma unroll
        for (int g = 0; g < G_; ++g) {
            const unsigned ab = ga[g] & ra[g];
            bitsArr[g] = (unsigned)((ab & 0xFFu) != 0) | ((unsigned)(((ab>>8) & 0xFFu) != 0) << 1)
                       | ((unsigned)(((ab>>16) & 0xFFu) != 0) << 2) | ((unsigned)((ab>>24) != 0) << 3);
        }
    }

    float s0=0.f,s1=0.f,s2=0.f,s3=0.f,s4=0.f,s5=0.f,s6=0.f,s7=0.f,s8=0.f;
    #pragma unroll
    for (int g = 0; g < G_; ++g) {
        const int p0 = base + g * 1024;
        unsigned bits = bitsArr[g] & ((unsigned)(vbits[p0 >> 6] >> (p0 & 63)) & 0xFu);
        if (bits) {
            const float4 dv = *reinterpret_cast<const float4*>(d0 + p0);
            const int r = p0 / W_;
            const int c0 = p0 - r * W_;
            const float pyb = (float)(r - 240) * rfy;
            while (bits) {
                const int j = __ffs(bits) - 1;
                bits &= bits - 1;
                const float d = (j == 0) ? dv.x : (j == 1) ? dv.y : (j == 2) ? dv.z : dv.w;
                const float ad = fabsf(d);
                const float px = (float)(c0 + j - 320) * ad * rfx;
                const float py = pyb * ad;
                s0 += px*px; s1 += px*py; s2 += px;
                s3 += py*py; s4 += py;    s5 += 1.0f;
                s6 += px*d;  s7 += py*d;  s8 += d;
            }
        }
    }

    float s[9] = {s0,s1,s2,s3,s4,s5,s6,s7,s8};
    #pragma unroll
    for (int off = 32; off > 0; off >>= 1) {
        #pragma unroll
        for (int i = 0; i < 9; ++i) s[i] += __shfl_down(s[i], off);
    }
    __shared__ float ls[4][9];
    const int wave = threadIdx.x >> 6, lane = threadIdx.x & 63;
    if (lane == 0) {
        #pragma unroll
        for (int i = 0; i < 9; ++i) ls[wave][i] = s[i];
    }
    __syncthreads();
    if (threadIdx.x == 0) {
        #pragma unroll
        for (int i = 0; i < 9; ++i)
            atomicAdd(&acc[n*12 + i], ls[0][i] + ls[1][i] + ls[2][i] + ls[3][i]);
    }
}

// ---- per-n 3x3 solve (Cramer, double), ok gate, mean(pd/den) --------------
__global__ void solve_k(const float* __restrict__ acc,
                        const float* __restrict__ d0,
                        const float* __restrict__ km,
                        const int* __restrict__ xp,
                        const int* __restrict__ yp,
                        float* __restrict__ abd)
{
    const int n = blockIdx.x * blockDim.x + threadIdx.x;
    if (n >= NN) return;
    const float* s = acc + n * 12;
    const double M00=s[0], M01=s[1], M02=s[2], M11=s[3], M12=s[4], M22=s[5];
    const double r0=s[6], r1=s[7], r2=s[8];
    const double cnt = M22;
    const double c00 = M11*M22 - M12*M12;
    const double c01 = M01*M22 - M12*M02;
    const double c02 = M01*M12 - M11*M02;
    const double det = M00*c00 - M01*c01 + M02*c02;
    const bool ok = (fabs(det) > 1e-8) && (cnt >= 3.0);
    float a = 0.f, b = 0.f, dc = 0.f, scale = 0.f;
    if (ok) {
        const double inv = 1.0 / det;
        const double t1 = r1*M22 - r2*M12;
        const double t2 = M01*r2 - r1*M02;
        const double x0 = (r0*c00 - M01*t1 + M02*(r1*M12 - r2*M11)) * inv;
        const double x1 = (M00*t1 - r0*c01 + M02*t2) * inv;
        const double x2 = (M00*(M11*r2 - r1*M12) - M01*t2 + r0*c02) * inv;
        a = (float)x0; b = (float)x1; dc = (float)x2;
        const float fx = km[0], fy = km[4];
        float sum = 0.0f;
        for (int k = 0; k < KK; ++k) {
            const int xi = xp[n*KK + k], yi = yp[n*KK + k];
            const float dd = d0[xi * W_ + yi];
            const float ad = fabsf(dd);
            const float ppx = (float)(yi - 320) * ad / fx;
            const float ppy = (float)(xi - 240) * ad / fy;
            const float den = a * ppx + b * ppy + dc;
            sum += dd / den;
        }
        scale = sum / (float)KK;
    }
    abd[n*8+0] = a; abd[n*8+1] = b; abd[n*8+2] = dc;
    abd[n*8+3] = scale;
    abd[n*8+4] = ok ? 1.0f : 0.0f;
}

// ---- scatter pass A: priority = max ok n per pixel, 4 queries/thread ------
__global__ __launch_bounds__(256) void prio_k(const int* __restrict__ xq,
                                              const int* __restrict__ yq,
                                              const float* __restrict__ abd,
                                              int* __restrict__ prio)
{
    const int idx = (blockIdx.x * 256 + threadIdx.x) * 4;   // QQ%4==0 -> same n
    const int n = idx >> 13;
    if (abd[n*8+4] == 0.0f) return;
    const int4 xs = *reinterpret_cast<const int4*>(xq + idx);
    const int4 ys = *reinterpret_cast<const int4*>(yq + idx);
    const int np = n + 1;
    atomicMax(prio + xs.x * W_ + ys.x, np);
    atomicMax(prio + xs.y * W_ + ys.y, np);
    atomicMax(prio + xs.z * W_ + ys.z, np);
    atomicMax(prio + xs.w * W_ + ys.w, np);
}

// ---- final: per pixel, winner n (or passthrough d0) -----------------------
__global__ __launch_bounds__(256) void final_k(const int* __restrict__ prio,
                                               const float* __restrict__ abd,
                                               const float* __restrict__ d0,
                                               const float* __restrict__ km,
                                               float* __restrict__ out)
{
    const int p0 = (blockIdx.x * 256 + threadIdx.x) * 4;
    const int4 pr4 = *reinterpret_cast<const int4*>(prio + p0);
    const float4 dv = *reinterpret_cast<const float4*>(d0 + p0);
    const float rfx = 1.0f / km[0], rfy = 1.0f / km[4];
    const int r = p0 / W_;
    const int c0 = p0 - r * W_;
    const float yv = (float)(r - 240) * rfy;
    const int pr[4] = {pr4.x, pr4.y, pr4.z, pr4.w};
    const float dd[4] = {dv.x, dv.y, dv.z, dv.w};
    float o[4];
    #pragma unroll
    for (int j = 0; j < 4; ++j) {
        float v = dd[j];
        if (pr[j] > 0) {
            const int n = pr[j] - 1;
            const float ad = fabsf(dd[j]);
            const float qx = (float)(c0 + j - 320) * ad * rfx;
            const float qy = yv * ad;
            v = (abd[n*8+0]*qx + abd[n*8+1]*qy + abd[n*8+2]) * abd[n*8+3];
        }
        o[j] = v;
    }
    *reinterpret_cast<float4*>(out + p0) = make_float4(o[0], o[1], o[2], o[3]);
}

extern "C" void kernel_launch(void* const* d_in, const int* in_sizes, int n_in,
                              void* d_out, int out_size, void* d_ws, size_t ws_size,
                              hipStream_t stream)
{
    const float* d0  = (const float*)d_in[0];
    const void*  gm  = d_in[1];
    const float* gtd = (const float*)d_in[2];
    const float* km  = (const float*)d_in[3];
    const void*  rm  = d_in[4];
    const int*   xq  = (const int*)d_in[5];
    const int*   yq  = (const int*)d_in[6];
    const int*   xp  = (const int*)d_in[7];
    const int*   yp  = (const int*)d_in[8];
    float* out = (float*)d_out;
    char*  ws  = (char*)d_ws;

    int* flag = (int*)(ws + WS_FLAG);
    float* acc = (float*)(ws + WS_ACC);
    float* abd = (float*)(ws + WS_ABD);
    unsigned long long* vbits = (unsigned long long*)(ws + WS_VBITS);
    int* prio = (int*)(ws + WS_PRIO);
    unsigned char* packed = (unsigned char*)(ws + WS_PACK);

    prep_k<<<HW / 256, 256, 0, stream>>>((const unsigned int*)gm, gtd, vbits, prio, acc, flag);
    if (ws_size >= WS_NEED) {
        compress_k<<<dim3(50, NN), 256, 0, stream>>>(gm, rm, flag, vbits, packed);
        reduce2_k<<<dim3(25, NN), 192, 0, stream>>>(d0, (const unsigned long long*)packed, km, acc);
    } else {
        reduce_k<<<dim3(HW / PIXB, NN), 256, 0, stream>>>(d0, gm, rm, km, flag, vbits, acc);
    }
    solve_k<<<2, 64, 0, stream>>>(acc, d0, km, xp, yp, abd);
    prio_k<<<(NN * QQ / 4) / 256, 256, 0, stream>>>(xq, yq, abd, prio);
    final_k<<<(HW / 4) / 256, 256, 0, stream>>>(prio, abd, d0, km, out);
}